// Round 6
// baseline (446.712 us; speedup 1.0000x reference)
//
#include <hip/hip_runtime.h>

typedef unsigned short u16;
typedef unsigned int u32;
typedef short bf16x8 __attribute__((ext_vector_type(8)));
typedef float f32x4 __attribute__((ext_vector_type(4)));
typedef unsigned int u32x2 __attribute__((ext_vector_type(2)));

#define D_MODEL 1024
#define NH 16
#define DK 64
#define DFF 4096
#define BATCH 2
#define SEQ 2048
#define BL (BATCH*SEQ)
#define NQKV 3072
// fold (1/sqrt(64)) * log2(e) into Q so softmax is raw exp2
#define Q_SCALE 0.18033688011f

__device__ __forceinline__ float bfraw2f(u16 u) {
    union { u32 i; float f; } c; c.i = ((u32)u) << 16; return c.f;
}
__device__ __forceinline__ u16 f2bfraw(float f) {
    union { float f; u32 i; } c; c.f = f;
    u32 i = c.i;
    u32 lsb = (i >> 16) & 1u;
    i += 0x7fffu + lsb;
    return (u16)(i >> 16);
}
__device__ __forceinline__ u32 fasu(float f) {
    union { float f; u32 i; } c; c.f = f; return c.i;
}
// pack two f32 -> (bf16(hi)<<16)|bf16(lo), round-to-nearest via +0x8000
__device__ __forceinline__ u32 pack_bf2(float lo, float hi) {
    return __builtin_amdgcn_perm(fasu(hi) + 0x8000u, fasu(lo) + 0x8000u,
                                 0x07060302u);
}
// async global->LDS 16B per lane (dest = wave-uniform base + lane*16)
__device__ __forceinline__ void gload_lds16(const u16* g, u16* l) {
    __builtin_amdgcn_global_load_lds(
        (const __attribute__((address_space(1))) void*)g,
        (__attribute__((address_space(3))) void*)l, 16, 0, 0);
}

// ---------------- f32 -> bf16 cast ----------------
__global__ __launch_bounds__(256) void cast_f32_bf16(const float* __restrict__ in,
                                                     u16* __restrict__ out) {
    int i = (blockIdx.x * 256 + threadIdx.x) * 4;
    f32x4 v = *(const f32x4*)&in[i];
#pragma unroll
    for (int j = 0; j < 4; j++) out[i + j] = f2bfraw(v[j]);
}

// ---------------- transposes (f32 weights -> bf16 B^T layout) ----------------

__global__ __launch_bounds__(256) void transpose2d(const float* __restrict__ in,
                                                   u16* __restrict__ out,
                                                   int R, int C) {
    __shared__ u16 t[64][65];
    int c0 = blockIdx.x * 64, r0 = blockIdx.y * 64;
    int col = threadIdx.x & 63, rr = threadIdx.x >> 6;
    for (int i = rr; i < 64; i += 4)
        t[i][col] = f2bfraw(in[(size_t)(r0 + i) * C + c0 + col]);
    __syncthreads();
    for (int i = rr; i < 64; i += 4)
        out[(size_t)(c0 + i) * R + r0 + col] = t[col][i];
}

__global__ __launch_bounds__(256) void transpose_wqkv(const float* __restrict__ Wq,
                                                      const float* __restrict__ Wk,
                                                      const float* __restrict__ Wv,
                                                      u16* __restrict__ out) {
    __shared__ u16 t[64][65];
    int d0 = blockIdx.x * 64;
    int h = blockIdx.y;
    int ms = blockIdx.z;
    const float* W = (ms == 0) ? Wq : (ms == 1) ? Wk : Wv;
    const float* src = W + (size_t)h * D_MODEL * DK;
    int col = threadIdx.x & 63, rr = threadIdx.x >> 6;
    for (int i = rr; i < 64; i += 4)
        t[i][col] = f2bfraw(src[(size_t)(d0 + i) * DK + col]);
    __syncthreads();
    u16* dst = out + (size_t)(ms * 1024 + h * 64) * D_MODEL;
    for (int i = rr; i < 64; i += 4)
        dst[(size_t)i * D_MODEL + d0 + col] = t[col][i];
}

__global__ __launch_bounds__(256) void transpose_v(const u16* __restrict__ qkv,
                                                   u16* __restrict__ vt) {
    __shared__ u16 t[64][65];
    int l0 = blockIdx.x * 64;
    int h = blockIdx.y;
    int b = blockIdx.z;
    int col = threadIdx.x & 63, rr = threadIdx.x >> 6;
    const u16* src = qkv + (size_t)(b * SEQ) * NQKV + 2048 + h * 64;
    for (int i = rr; i < 64; i += 4)
        t[i][col] = src[(size_t)(l0 + i) * NQKV + col];
    __syncthreads();
    u16* dst = vt + (size_t)((b * NH + h) * 64) * SEQ;
    for (int i = rr; i < 64; i += 4)
        dst[(size_t)i * SEQ + l0 + col] = t[col][i];
}

__global__ __launch_bounds__(256) void concat_bias(const float* __restrict__ bq,
                                                   const float* __restrict__ bk,
                                                   const float* __restrict__ bv,
                                                   float* __restrict__ out) {
    int i = blockIdx.x * 256 + threadIdx.x;
    out[i] = (i < 1024) ? bq[i] : (i < 2048) ? bk[i - 1024] : bv[i - 2048];
}

// ---------------- GEMM: C[M][N] = A[M][K] @ Bt[N][K]^T ----------------
// m97 structure: 128x128 tile, BK=64, unpadded LDS, global_load_lds width 16.
// SPLITK>1: blockIdx.z handles K-slice z, writes f32 partial to Cout+z*M*N.
// SCALEQ: multiply cols<1024 by Q_SCALE (QKV gemm only).

template <int OUT_F32, int RELU, int HASBIAS, int SPLITK, int SCALEQ>
__global__ __launch_bounds__(256, 4) void gemm_bt(const u16* __restrict__ A,
                                                  const u16* __restrict__ Bt,
                                                  const float* __restrict__ bias,
                                                  void* __restrict__ Cout,
                                                  int M, int N, int K) {
    __shared__ __attribute__((aligned(16))) u16 As[128 * 64];
    __shared__ __attribute__((aligned(16))) u16 Bs[128 * 64];
    const int tid = threadIdx.x;
    const int lane = tid & 63, wid = tid >> 6;
    const int quad = lane >> 4, l16 = lane & 15;
    const int m0 = blockIdx.x * 128, n0 = blockIdx.y * 128;
    const int z = (SPLITK > 1) ? blockIdx.z : 0;
    const int Klen = K / SPLITK;
    const int kend = (z + 1) * Klen;
    const int wm = (wid >> 1) * 64, wn = (wid & 1) * 64;

    f32x4 acc[4][4];
#pragma unroll
    for (int i = 0; i < 4; i++)
#pragma unroll
        for (int j = 0; j < 4; j++) acc[i][j] = (f32x4){0.f, 0.f, 0.f, 0.f};

    // chunk c = wid*4+p: rows c*8..c*8+7, lane i at row c*8+(i>>3), col (i&7)*8
    const int srow = lane >> 3, scol = (lane & 7) * 8;

    for (int kb = z * Klen; kb < kend; kb += 64) {
#pragma unroll
        for (int p = 0; p < 4; p++) {
            int c = wid * 4 + p;
            int row = c * 8 + srow;
            gload_lds16(&A[(size_t)(m0 + row) * K + kb + scol], &As[c * 512]);
            gload_lds16(&Bt[(size_t)(n0 + row) * K + kb + scol], &Bs[c * 512]);
        }
        __syncthreads();
#pragma unroll
        for (int kh = 0; kh < 2; kh++) {
            bf16x8 af[4], bf[4];
#pragma unroll
            for (int t = 0; t < 4; t++) {
                af[t] = *(const bf16x8*)&As[(wm + t * 16 + l16) * 64 + kh * 32 + quad * 8];
                bf[t] = *(const bf16x8*)&Bs[(wn + t * 16 + l16) * 64 + kh * 32 + quad * 8];
            }
#pragma unroll
            for (int i = 0; i < 4; i++)
#pragma unroll
                for (int j = 0; j < 4; j++)
                    acc[i][j] = __builtin_amdgcn_mfma_f32_16x16x32_bf16(
                        af[i], bf[j], acc[i][j], 0, 0, 0);
        }
        __syncthreads();
    }

    float* outf = (float*)Cout + (size_t)z * M * N;
#pragma unroll
    for (int i = 0; i < 4; i++) {
#pragma unroll
        for (int j = 0; j < 4; j++) {
#pragma unroll
            for (int r = 0; r < 4; r++) {
                int row = m0 + wm + i * 16 + quad * 4 + r;
                int col = n0 + wn + j * 16 + l16;
                float v = acc[i][j][r];
                if (HASBIAS) v += bias[col];
                if (RELU) v = v > 0.f ? v : 0.f;
                if (SCALEQ && col < 1024) v *= Q_SCALE;
                if (OUT_F32)
                    outf[(size_t)row * N + col] = v;
                else
                    ((u16*)Cout)[(size_t)row * N + col] = f2bfraw(v);
            }
        }
    }
}

// ---------------- flash attention, S^T form ----------------
// grid (SEQ/128, NH, BATCH); 4 waves/block; wave owns 32 q rows.
// K staged via global_load_lds (unpadded, m97 pattern); V read direct from
// global (L2, 4-wave reuse); P per-wave in LDS. LDS=50KB -> 3 blocks/CU.
__global__ __launch_bounds__(256, 3) void attn_kernel(const u16* __restrict__ qkv,
                                                      const u16* __restrict__ vt,
                                                      u16* __restrict__ O) {
    constexpr int LDP = 136;
    __shared__ __attribute__((aligned(16))) u16 Ks[128 * 64];
    __shared__ __attribute__((aligned(16))) u16 Ps[4][32 * LDP];

    const int tid = threadIdx.x;
    const int lane = tid & 63, wid = tid >> 6;
    const int quad = lane >> 4, l16 = lane & 15;
    const int b = blockIdx.z, h = blockIdx.y;
    const int q0 = blockIdx.x * 128 + wid * 32;

    // Q fragments (B-operand: n=q=l16, k=quad*8+j); Q pre-scaled by Q_SCALE
    bf16x8 qf[2][2];
#pragma unroll
    for (int qt = 0; qt < 2; qt++) {
        const size_t qrow = (size_t)(b * SEQ + q0 + qt * 16 + l16) * NQKV + h * DK;
        qf[qt][0] = *(const bf16x8*)&qkv[qrow + quad * 8];
        qf[qt][1] = *(const bf16x8*)&qkv[qrow + 32 + quad * 8];
    }
    const u16* Kbase = qkv + (size_t)(b * SEQ) * NQKV + D_MODEL + h * DK;
    const u16* Vbase = vt + (size_t)((b * NH + h) * DK) * SEQ;

    const int srow = lane >> 3, scol = (lane & 7) * 8;

    f32x4 oacc[4][2];
#pragma unroll
    for (int d = 0; d < 4; d++) {
        oacc[d][0] = (f32x4){0.f, 0.f, 0.f, 0.f};
        oacc[d][1] = (f32x4){0.f, 0.f, 0.f, 0.f};
    }
    float lr[2] = {0.f, 0.f};
    const f32x4 Z = {0.f, 0.f, 0.f, 0.f};

    for (int kt = 0; kt < SEQ; kt += 128) {
        // ---- stage K[128][64] via async global->LDS, unpadded ----
#pragma unroll
        for (int p = 0; p < 4; p++) {
            int c = wid * 4 + p;
            gload_lds16(&Kbase[(size_t)(kt + c * 8 + srow) * NQKV + scol],
                        &Ks[c * 512]);
        }
        __syncthreads();

        // ---- S^T = K·Q^T : k=nt*16+quad*4+r, q=qt*16+l16 ----
        f32x4 sacc[8][2];
#pragma unroll
        for (int nt = 0; nt < 8; nt++) {
            const u16* kr = &Ks[(nt * 16 + l16) * 64];
            bf16x8 kf0 = *(const bf16x8*)&kr[quad * 8];
            bf16x8 kf1 = *(const bf16x8*)&kr[32 + quad * 8];
#pragma unroll
            for (int qt = 0; qt < 2; qt++) {
                f32x4 s0 = __builtin_amdgcn_mfma_f32_16x16x32_bf16(kf0, qf[qt][0], Z, 0, 0, 0);
                sacc[nt][qt] = __builtin_amdgcn_mfma_f32_16x16x32_bf16(kf1, qf[qt][1], s0, 0, 0, 0);
            }
        }

        // ---- softmax: raw exp2 (scale folded into Q), per-lane sums ----
#pragma unroll
        for (int qt = 0; qt < 2; qt++) {
            u16* prow = &Ps[wid][(qt * 16 + l16) * LDP];
#pragma unroll
            for (int nt = 0; nt < 8; nt++) {
                float p0 = exp2f(sacc[nt][qt][0]);
                float p1 = exp2f(sacc[nt][qt][1]);
                float p2 = exp2f(sacc[nt][qt][2]);
                float p3 = exp2f(sacc[nt][qt][3]);
                lr[qt] += (p0 + p1) + (p2 + p3);
                u32x2 w;
                w.x = pack_bf2(p0, p1);
                w.y = pack_bf2(p2, p3);
                *(u32x2*)&prow[nt * 16 + quad * 4] = w;
            }
        }
        // P write->read is same-wave LDS (lgkm-ordered): no barrier needed.

        // ---- O^T += V^T·P^T : A=V (direct global b128, loop-invariant addrs) ----
#pragma unroll
        for (int ks = 0; ks < 4; ks++) {
            bf16x8 pf0 = *(const bf16x8*)&Ps[wid][l16 * LDP + ks * 32 + quad * 8];
            bf16x8 pf1 = *(const bf16x8*)&Ps[wid][(16 + l16) * LDP + ks * 32 + quad * 8];
#pragma unroll
            for (int d = 0; d < 4; d++) {
                bf16x8 vf = *(const bf16x8*)&Vbase[(size_t)(d * 16 + l16) * SEQ +
                                                   kt + ks * 32 + quad * 8];
                oacc[d][0] = __builtin_amdgcn_mfma_f32_16x16x32_bf16(vf, pf0, oacc[d][0], 0, 0, 0);
                oacc[d][1] = __builtin_amdgcn_mfma_f32_16x16x32_bf16(vf, pf1, oacc[d][1], 0, 0, 0);
            }
        }
        __syncthreads();  // all waves done with Ks before restage
    }

#pragma unroll
    for (int qt = 0; qt < 2; qt++) {
        lr[qt] += __shfl_xor(lr[qt], 16, 64);
        lr[qt] += __shfl_xor(lr[qt], 32, 64);
    }

#pragma unroll
    for (int qt = 0; qt < 2; qt++) {
        float iv = 1.f / lr[qt];
        size_t row = (size_t)(b * SEQ + q0 + qt * 16 + l16);
#pragma unroll
        for (int d = 0; d < 4; d++) {
            float o0 = oacc[d][qt][0] * iv, o1 = oacc[d][qt][1] * iv;
            float o2 = oacc[d][qt][2] * iv, o3 = oacc[d][qt][3] * iv;
            u32x2 w;
            w.x = ((u32)f2bfraw(o1) << 16) | f2bfraw(o0);
            w.y = ((u32)f2bfraw(o3) << 16) | f2bfraw(o2);
            *(u32x2*)&O[row * D_MODEL + h * DK + d * 16 + quad * 4] = w;
        }
    }
}

// ---------------- LayerNorm(a + b + c), f32 residual stream ----------------
__global__ __launch_bounds__(256) void ln3_kernel(const float* __restrict__ xa,
                                                  const float* __restrict__ xb,
                                                  const float* __restrict__ xc,
                                                  const float* __restrict__ g,
                                                  const float* __restrict__ be,
                                                  u16* __restrict__ out_bf,
                                                  float* __restrict__ out_f) {
    int row = blockIdx.x;
    int tid = threadIdx.x;
    const float* pa = xa + (size_t)row * D_MODEL;
    const float* pb = xb + (size_t)row * D_MODEL;
    const float* pc = xc + (size_t)row * D_MODEL;
    int c = tid * 4;
    f32x4 av = *(const f32x4*)&pa[c];
    f32x4 bv = *(const f32x4*)&pb[c];
    f32x4 cv = *(const f32x4*)&pc[c];
    float v[4];
    float s = 0.f, ss = 0.f;
#pragma unroll
    for (int i = 0; i < 4; i++) {
        v[i] = av[i] + bv[i] + cv[i];
        s += v[i];
        ss += v[i] * v[i];
    }
#pragma unroll
    for (int off = 32; off; off >>= 1) {
        s += __shfl_down(s, off, 64);
        ss += __shfl_down(ss, off, 64);
    }
    __shared__ float red[8];
    int wid = tid >> 6, lane = tid & 63;
    if (lane == 0) { red[wid] = s; red[4 + wid] = ss; }
    __syncthreads();
    if (tid == 0) {
        red[0] = red[0] + red[1] + red[2] + red[3];
        red[4] = red[4] + red[5] + red[6] + red[7];
    }
    __syncthreads();
    float mu = red[0] * (1.f / D_MODEL);
    float var = red[4] * (1.f / D_MODEL) - mu * mu;
    float rs = rsqrtf(var + 1e-5f);
#pragma unroll
    for (int i = 0; i < 4; i++) {
        float o = (v[i] - mu) * rs * g[c + i] + be[c + i];
        if (out_f) out_f[(size_t)row * D_MODEL + c + i] = o;
        if (out_bf) out_bf[(size_t)row * D_MODEL + c + i] = f2bfraw(o);
    }
}

// ---------------- launch ----------------
extern "C" void kernel_launch(void* const* d_in, const int* in_sizes, int n_in,
                              void* d_out, int out_size, void* d_ws, size_t ws_size,
                              hipStream_t stream) {
    const float* x   = (const float*)d_in[0];
    const float* Wq  = (const float*)d_in[1];
    const float* bq  = (const float*)d_in[2];
    const float* Wk  = (const float*)d_in[3];
    const float* bk  = (const float*)d_in[4];
    const float* Wv  = (const float*)d_in[5];
    const float* bv  = (const float*)d_in[6];
    const float* Wo  = (const float*)d_in[7];
    const float* g1  = (const float*)d_in[8];
    const float* be1 = (const float*)d_in[9];
    const float* W1  = (const float*)d_in[10];
    const float* b1  = (const float*)d_in[11];
    const float* W2  = (const float*)d_in[12];
    const float* g2  = (const float*)d_in[13];
    const float* be2 = (const float*)d_in[14];

    char* w = (char*)d_ws;
    auto alloc = [&](size_t bytes) {
        char* p = w;
        w += (bytes + 255) & ~(size_t)255;
        return p;
    };
    u16* wqkv_t = (u16*)alloc((size_t)NQKV * D_MODEL * 2);
    u16* wo_t   = (u16*)alloc((size_t)D_MODEL * D_MODEL * 2);
    u16* w1_t   = (u16*)alloc((size_t)DFF * D_MODEL * 2);
    u16* w2_t   = (u16*)alloc((size_t)D_MODEL * DFF * 2);
    float* bqkv = (float*)alloc((size_t)NQKV * 4);
    u16* x_bf   = (u16*)alloc((size_t)BL * D_MODEL * 2);
    u16* qkvbuf = (u16*)alloc((size_t)BL * NQKV * 2);
    u16* vtbuf  = (u16*)alloc((size_t)BATCH * NH * DK * SEQ * 2);
    u16* obuf   = (u16*)alloc((size_t)BL * D_MODEL * 2);
    float* mha_p = (float*)alloc((size_t)2 * BL * D_MODEL * 4);  // split-K partials
    u16* h1_bf  = (u16*)alloc((size_t)BL * D_MODEL * 2);
    float* h1_f = (float*)alloc((size_t)BL * D_MODEL * 4);
    u16* ffa    = (u16*)alloc((size_t)BL * DFF * 2);
    float* ffb_p = (float*)alloc((size_t)2 * BL * D_MODEL * 4);  // split-K partials

    cast_f32_bf16<<<dim3(BL * D_MODEL / 1024), 256, 0, stream>>>(x, x_bf);
    transpose_wqkv<<<dim3(16, 16, 3), 256, 0, stream>>>(Wq, Wk, Wv, wqkv_t);
    transpose2d<<<dim3(16, 16), 256, 0, stream>>>(Wo, wo_t, 1024, 1024);
    transpose2d<<<dim3(64, 16), 256, 0, stream>>>(W1, w1_t, 1024, 4096);
    transpose2d<<<dim3(16, 64), 256, 0, stream>>>(W2, w2_t, 4096, 1024);
    concat_bias<<<dim3(12), 256, 0, stream>>>(bq, bk, bv, bqkv);

    // QKV = x @ Wqkv^T + bias -> bf16 [4096][3072]; Q cols pre-scaled
    gemm_bt<0, 0, 1, 1, 1><<<dim3(32, 24), 256, 0, stream>>>(x_bf, wqkv_t, bqkv,
                                                             qkvbuf, BL, NQKV, D_MODEL);
    transpose_v<<<dim3(32, 16, 2), 256, 0, stream>>>(qkvbuf, vtbuf);
    // flash attention -> O bf16 [4096][1024]
    attn_kernel<<<dim3(16, 16, 2), 256, 0, stream>>>(qkvbuf, vtbuf, obuf);
    // mha partials = O @ Wo (split-K=2) -> f32 x2
    gemm_bt<1, 0, 0, 2, 0><<<dim3(32, 8, 2), 256, 0, stream>>>(obuf, wo_t, nullptr,
                                                               mha_p, BL, D_MODEL, D_MODEL);
    // h1 = LN(x + mha_p0 + mha_p1)
    ln3_kernel<<<dim3(BL), 256, 0, stream>>>(x, mha_p, mha_p + (size_t)BL * D_MODEL,
                                             g1, be1, h1_bf, h1_f);
    // ffa = relu(h1 @ W1 + b1) -> bf16 [4096][4096]
    gemm_bt<0, 1, 1, 1, 0><<<dim3(32, 32), 256, 0, stream>>>(h1_bf, w1_t, b1, ffa,
                                                             BL, DFF, D_MODEL);
    // ffb partials = ffa @ W2 (split-K=2) -> f32 x2
    gemm_bt<1, 0, 0, 2, 0><<<dim3(32, 8, 2), 256, 0, stream>>>(ffa, w2_t, nullptr,
                                                               ffb_p, BL, D_MODEL, DFF);
    // out = LN(h1 + ffb_p0 + ffb_p1)
    ln3_kernel<<<dim3(BL), 256, 0, stream>>>(h1_f, ffb_p, ffb_p + (size_t)BL * D_MODEL,
                                             g2, be2, nullptr, (float*)d_out);
}

// Round 7
// 403.322 us; speedup vs baseline: 1.1076x; 1.1076x over previous
//
#include <hip/hip_runtime.h>

typedef unsigned short u16;
typedef unsigned int u32;
typedef short bf16x8 __attribute__((ext_vector_type(8)));
typedef float f32x4 __attribute__((ext_vector_type(4)));
typedef unsigned int u32x2 __attribute__((ext_vector_type(2)));

#define D_MODEL 1024
#define NH 16
#define DK 64
#define DFF 4096
#define BATCH 2
#define SEQ 2048
#define BL (BATCH*SEQ)
#define NQKV 3072
// fold (1/sqrt(64)) * log2(e) into Q so softmax is raw exp2
#define Q_SCALE 0.18033688011f

__device__ __forceinline__ float bfraw2f(u16 u) {
    union { u32 i; float f; } c; c.i = ((u32)u) << 16; return c.f;
}
__device__ __forceinline__ u16 f2bfraw(float f) {
    union { float f; u32 i; } c; c.f = f;
    u32 i = c.i;
    u32 lsb = (i >> 16) & 1u;
    i += 0x7fffu + lsb;
    return (u16)(i >> 16);
}
__device__ __forceinline__ u32 fasu(float f) {
    union { float f; u32 i; } c; c.f = f; return c.i;
}
// pack two f32 -> (bf16(hi)<<16)|bf16(lo), round-to-nearest via +0x8000
__device__ __forceinline__ u32 pack_bf2(float lo, float hi) {
    return __builtin_amdgcn_perm(fasu(hi) + 0x8000u, fasu(lo) + 0x8000u,
                                 0x07060302u);
}
// async global->LDS 16B per lane (dest = wave-uniform base + lane*16)
__device__ __forceinline__ void gload_lds16(const u16* g, u16* l) {
    __builtin_amdgcn_global_load_lds(
        (const __attribute__((address_space(1))) void*)g,
        (__attribute__((address_space(3))) void*)l, 16, 0, 0);
}

// ---------------- f32 -> bf16 cast ----------------
__global__ __launch_bounds__(256) void cast_f32_bf16(const float* __restrict__ in,
                                                     u16* __restrict__ out) {
    int i = (blockIdx.x * 256 + threadIdx.x) * 4;
    f32x4 v = *(const f32x4*)&in[i];
#pragma unroll
    for (int j = 0; j < 4; j++) out[i + j] = f2bfraw(v[j]);
}

// ---------------- transposes (f32 weights -> bf16 B^T layout) ----------------

__global__ __launch_bounds__(256) void transpose2d(const float* __restrict__ in,
                                                   u16* __restrict__ out,
                                                   int R, int C) {
    __shared__ u16 t[64][65];
    int c0 = blockIdx.x * 64, r0 = blockIdx.y * 64;
    int col = threadIdx.x & 63, rr = threadIdx.x >> 6;
    for (int i = rr; i < 64; i += 4)
        t[i][col] = f2bfraw(in[(size_t)(r0 + i) * C + c0 + col]);
    __syncthreads();
    for (int i = rr; i < 64; i += 4)
        out[(size_t)(c0 + i) * R + r0 + col] = t[col][i];
}

__global__ __launch_bounds__(256) void transpose_wqkv(const float* __restrict__ Wq,
                                                      const float* __restrict__ Wk,
                                                      const float* __restrict__ Wv,
                                                      u16* __restrict__ out) {
    __shared__ u16 t[64][65];
    int d0 = blockIdx.x * 64;
    int h = blockIdx.y;
    int ms = blockIdx.z;
    const float* W = (ms == 0) ? Wq : (ms == 1) ? Wk : Wv;
    const float* src = W + (size_t)h * D_MODEL * DK;
    int col = threadIdx.x & 63, rr = threadIdx.x >> 6;
    for (int i = rr; i < 64; i += 4)
        t[i][col] = f2bfraw(src[(size_t)(d0 + i) * DK + col]);
    __syncthreads();
    u16* dst = out + (size_t)(ms * 1024 + h * 64) * D_MODEL;
    for (int i = rr; i < 64; i += 4)
        dst[(size_t)i * D_MODEL + d0 + col] = t[col][i];
}

__global__ __launch_bounds__(256) void transpose_v(const u16* __restrict__ qkv,
                                                   u16* __restrict__ vt) {
    __shared__ u16 t[64][65];
    int l0 = blockIdx.x * 64;
    int h = blockIdx.y;
    int b = blockIdx.z;
    int col = threadIdx.x & 63, rr = threadIdx.x >> 6;
    const u16* src = qkv + (size_t)(b * SEQ) * NQKV + 2048 + h * 64;
    for (int i = rr; i < 64; i += 4)
        t[i][col] = src[(size_t)(l0 + i) * NQKV + col];
    __syncthreads();
    u16* dst = vt + (size_t)((b * NH + h) * 64) * SEQ;
    for (int i = rr; i < 64; i += 4)
        dst[(size_t)i * SEQ + l0 + col] = t[col][i];
}

__global__ __launch_bounds__(256) void concat_bias(const float* __restrict__ bq,
                                                   const float* __restrict__ bk,
                                                   const float* __restrict__ bv,
                                                   float* __restrict__ out) {
    int i = blockIdx.x * 256 + threadIdx.x;
    out[i] = (i < 1024) ? bq[i] : (i < 2048) ? bk[i - 1024] : bv[i - 2048];
}

// ---------------- GEMM: C[M][N] = A[M][K] @ Bt[N][K]^T ----------------
// m97 structure: 128x128 tile, BK=64, unpadded LDS, global_load_lds width 16.

template <int OUT_F32, int RELU, int HASBIAS, int SPLITK, int SCALEQ>
__global__ __launch_bounds__(256, 4) void gemm_bt(const u16* __restrict__ A,
                                                  const u16* __restrict__ Bt,
                                                  const float* __restrict__ bias,
                                                  void* __restrict__ Cout,
                                                  int M, int N, int K) {
    __shared__ __attribute__((aligned(16))) u16 As[128 * 64];
    __shared__ __attribute__((aligned(16))) u16 Bs[128 * 64];
    const int tid = threadIdx.x;
    const int lane = tid & 63, wid = tid >> 6;
    const int quad = lane >> 4, l16 = lane & 15;
    const int m0 = blockIdx.x * 128, n0 = blockIdx.y * 128;
    const int z = (SPLITK > 1) ? blockIdx.z : 0;
    const int Klen = K / SPLITK;
    const int kend = (z + 1) * Klen;
    const int wm = (wid >> 1) * 64, wn = (wid & 1) * 64;

    f32x4 acc[4][4];
#pragma unroll
    for (int i = 0; i < 4; i++)
#pragma unroll
        for (int j = 0; j < 4; j++) acc[i][j] = (f32x4){0.f, 0.f, 0.f, 0.f};

    const int srow = lane >> 3, scol = (lane & 7) * 8;

    for (int kb = z * Klen; kb < kend; kb += 64) {
#pragma unroll
        for (int p = 0; p < 4; p++) {
            int c = wid * 4 + p;
            int row = c * 8 + srow;
            gload_lds16(&A[(size_t)(m0 + row) * K + kb + scol], &As[c * 512]);
            gload_lds16(&Bt[(size_t)(n0 + row) * K + kb + scol], &Bs[c * 512]);
        }
        __syncthreads();
#pragma unroll
        for (int kh = 0; kh < 2; kh++) {
            bf16x8 af[4], bf[4];
#pragma unroll
            for (int t = 0; t < 4; t++) {
                af[t] = *(const bf16x8*)&As[(wm + t * 16 + l16) * 64 + kh * 32 + quad * 8];
                bf[t] = *(const bf16x8*)&Bs[(wn + t * 16 + l16) * 64 + kh * 32 + quad * 8];
            }
#pragma unroll
            for (int i = 0; i < 4; i++)
#pragma unroll
                for (int j = 0; j < 4; j++)
                    acc[i][j] = __builtin_amdgcn_mfma_f32_16x16x32_bf16(
                        af[i], bf[j], acc[i][j], 0, 0, 0);
        }
        __syncthreads();
    }

    float* outf = (float*)Cout + (size_t)z * M * N;
#pragma unroll
    for (int i = 0; i < 4; i++) {
#pragma unroll
        for (int j = 0; j < 4; j++) {
#pragma unroll
            for (int r = 0; r < 4; r++) {
                int row = m0 + wm + i * 16 + quad * 4 + r;
                int col = n0 + wn + j * 16 + l16;
                float v = acc[i][j][r];
                if (HASBIAS) v += bias[col];
                if (RELU) v = v > 0.f ? v : 0.f;
                if (SCALEQ && col < 1024) v *= Q_SCALE;
                if (OUT_F32)
                    outf[(size_t)row * N + col] = v;
                else
                    ((u16*)Cout)[(size_t)row * N + col] = f2bfraw(v);
            }
        }
    }
}

// ---------------- flash attention, S^T form, qt-split pipeline ----------------
// grid (SEQ/128, NH, BATCH); 4 waves/block; wave owns 32 q rows (2 passes of 16).
// K,V staged coalesced reg->padded LDS (r5-proven); P per-wave 16 rows.
// LDS = 18432 + 17408 + 17408 = 53248 B -> 3 blocks/CU.
__global__ __launch_bounds__(256, 3) void attn_kernel(const u16* __restrict__ qkv,
                                                      const u16* __restrict__ vt,
                                                      u16* __restrict__ O) {
    constexpr int LDK = 72;    // 144B row stride
    constexpr int LDV = 136;   // 272B row stride
    constexpr int LDP = 136;
    __shared__ __attribute__((aligned(16))) u16 Ks[128 * LDK];
    __shared__ __attribute__((aligned(16))) u16 Vs[64 * LDV];
    __shared__ __attribute__((aligned(16))) u16 Ps[4][16 * LDP];

    const int tid = threadIdx.x;
    const int lane = tid & 63, wid = tid >> 6;
    const int quad = lane >> 4, l16 = lane & 15;
    const int b = blockIdx.z, h = blockIdx.y;
    const int q0 = blockIdx.x * 128 + wid * 32;

    // Q fragments (B-operand: n=q=l16, k=quad*8+j); Q pre-scaled by Q_SCALE
    bf16x8 qf[2][2];
#pragma unroll
    for (int qt = 0; qt < 2; qt++) {
        const size_t qrow = (size_t)(b * SEQ + q0 + qt * 16 + l16) * NQKV + h * DK;
        qf[qt][0] = *(const bf16x8*)&qkv[qrow + quad * 8];
        qf[qt][1] = *(const bf16x8*)&qkv[qrow + 32 + quad * 8];
    }
    const u16* Kbase = qkv + (size_t)(b * SEQ) * NQKV + D_MODEL + h * DK;
    const u16* Vbase = vt + (size_t)((b * NH + h) * DK) * SEQ;

    f32x4 oacc[4][2];
#pragma unroll
    for (int d = 0; d < 4; d++) {
        oacc[d][0] = (f32x4){0.f, 0.f, 0.f, 0.f};
        oacc[d][1] = (f32x4){0.f, 0.f, 0.f, 0.f};
    }
    float lr[2] = {0.f, 0.f};
    const f32x4 Z = {0.f, 0.f, 0.f, 0.f};

    for (int kt = 0; kt < SEQ; kt += 128) {
        // ---- stage K[128][64], V^T[64][128]: coalesced b128 reg round-trip ----
        bf16x8 kreg[4], vreg[4];
#pragma unroll
        for (int p = 0; p < 4; p++) {
            int s = p * 256 + tid;
            kreg[p] = *(const bf16x8*)&Kbase[(size_t)(kt + (s >> 3)) * NQKV + (s & 7) * 8];
            vreg[p] = *(const bf16x8*)&Vbase[(size_t)(s >> 4) * SEQ + kt + (s & 15) * 8];
        }
#pragma unroll
        for (int p = 0; p < 4; p++) {
            int s = p * 256 + tid;
            *(bf16x8*)&Ks[(s >> 3) * LDK + (s & 7) * 8] = kreg[p];
            *(bf16x8*)&Vs[(s >> 4) * LDV + (s & 15) * 8] = vreg[p];
        }
        __syncthreads();

#pragma unroll
        for (int qt = 0; qt < 2; qt++) {
            // ---- S^T = K·Q^T : lane holds k=nt*16+quad*4+r, q=qt*16+l16 ----
            f32x4 sacc[8];
#pragma unroll
            for (int nt = 0; nt < 8; nt++) {
                const u16* kr = &Ks[(nt * 16 + l16) * LDK];
                bf16x8 kf0 = *(const bf16x8*)&kr[quad * 8];
                bf16x8 kf1 = *(const bf16x8*)&kr[32 + quad * 8];
                f32x4 s0 = __builtin_amdgcn_mfma_f32_16x16x32_bf16(kf0, qf[qt][0], Z, 0, 0, 0);
                sacc[nt] = __builtin_amdgcn_mfma_f32_16x16x32_bf16(kf1, qf[qt][1], s0, 0, 0, 0);
            }

            // ---- softmax: raw exp2 (scale folded into Q), per-lane sums ----
            u16* prow = &Ps[wid][l16 * LDP];
#pragma unroll
            for (int nt = 0; nt < 8; nt++) {
                float p0 = exp2f(sacc[nt][0]);
                float p1 = exp2f(sacc[nt][1]);
                float p2 = exp2f(sacc[nt][2]);
                float p3 = exp2f(sacc[nt][3]);
                lr[qt] += (p0 + p1) + (p2 + p3);
                u32x2 w;
                w.x = pack_bf2(p0, p1);
                w.y = pack_bf2(p2, p3);
                *(u32x2*)&prow[nt * 16 + quad * 4] = w;
            }
            // P write->read is same-wave LDS (lgkm-ordered): no barrier needed.

            // ---- O^T += V^T·P^T : A=V frag (LDS), B=P frag (LDS) ----
#pragma unroll
            for (int ks = 0; ks < 4; ks++) {
                bf16x8 pf = *(const bf16x8*)&Ps[wid][l16 * LDP + ks * 32 + quad * 8];
#pragma unroll
                for (int d = 0; d < 4; d++) {
                    bf16x8 vf = *(const bf16x8*)&Vs[(d * 16 + l16) * LDV + ks * 32 + quad * 8];
                    oacc[d][qt] = __builtin_amdgcn_mfma_f32_16x16x32_bf16(vf, pf, oacc[d][qt], 0, 0, 0);
                }
            }
        }
        __syncthreads();  // all waves done with Ks/Vs before restage
    }

    // lane's lr covers its quad's 32 k's per tile; reduce across quads
#pragma unroll
    for (int qt = 0; qt < 2; qt++) {
        lr[qt] += __shfl_xor(lr[qt], 16, 64);
        lr[qt] += __shfl_xor(lr[qt], 32, 64);
    }

    // O^T C-layout: col=q=l16(+qt*16), row=dv=d*16+quad*4+r -> b64 stores
#pragma unroll
    for (int qt = 0; qt < 2; qt++) {
        float iv = 1.f / lr[qt];
        size_t row = (size_t)(b * SEQ + q0 + qt * 16 + l16);
#pragma unroll
        for (int d = 0; d < 4; d++) {
            float o0 = oacc[d][qt][0] * iv, o1 = oacc[d][qt][1] * iv;
            float o2 = oacc[d][qt][2] * iv, o3 = oacc[d][qt][3] * iv;
            u32x2 w;
            w.x = ((u32)f2bfraw(o1) << 16) | f2bfraw(o0);
            w.y = ((u32)f2bfraw(o3) << 16) | f2bfraw(o2);
            *(u32x2*)&O[row * D_MODEL + h * DK + d * 16 + quad * 4] = w;
        }
    }
}

// ---------------- LayerNorm(a + b + c), f32 residual stream ----------------
__global__ __launch_bounds__(256) void ln3_kernel(const float* __restrict__ xa,
                                                  const float* __restrict__ xb,
                                                  const float* __restrict__ xc,
                                                  const float* __restrict__ g,
                                                  const float* __restrict__ be,
                                                  u16* __restrict__ out_bf,
                                                  float* __restrict__ out_f) {
    int row = blockIdx.x;
    int tid = threadIdx.x;
    const float* pa = xa + (size_t)row * D_MODEL;
    const float* pb = xb + (size_t)row * D_MODEL;
    const float* pc = xc + (size_t)row * D_MODEL;
    int c = tid * 4;
    f32x4 av = *(const f32x4*)&pa[c];
    f32x4 bv = *(const f32x4*)&pb[c];
    f32x4 cv = *(const f32x4*)&pc[c];
    float v[4];
    float s = 0.f, ss = 0.f;
#pragma unroll
    for (int i = 0; i < 4; i++) {
        v[i] = av[i] + bv[i] + cv[i];
        s += v[i];
        ss += v[i] * v[i];
    }
#pragma unroll
    for (int off = 32; off; off >>= 1) {
        s += __shfl_down(s, off, 64);
        ss += __shfl_down(ss, off, 64);
    }
    __shared__ float red[8];
    int wid = tid >> 6, lane = tid & 63;
    if (lane == 0) { red[wid] = s; red[4 + wid] = ss; }
    __syncthreads();
    if (tid == 0) {
        red[0] = red[0] + red[1] + red[2] + red[3];
        red[4] = red[4] + red[5] + red[6] + red[7];
    }
    __syncthreads();
    float mu = red[0] * (1.f / D_MODEL);
    float var = red[4] * (1.f / D_MODEL) - mu * mu;
    float rs = rsqrtf(var + 1e-5f);
#pragma unroll
    for (int i = 0; i < 4; i++) {
        float o = (v[i] - mu) * rs * g[c + i] + be[c + i];
        if (out_f) out_f[(size_t)row * D_MODEL + c + i] = o;
        if (out_bf) out_bf[(size_t)row * D_MODEL + c + i] = f2bfraw(o);
    }
}

// ---------------- launch ----------------
extern "C" void kernel_launch(void* const* d_in, const int* in_sizes, int n_in,
                              void* d_out, int out_size, void* d_ws, size_t ws_size,
                              hipStream_t stream) {
    const float* x   = (const float*)d_in[0];
    const float* Wq  = (const float*)d_in[1];
    const float* bq  = (const float*)d_in[2];
    const float* Wk  = (const float*)d_in[3];
    const float* bk  = (const float*)d_in[4];
    const float* Wv  = (const float*)d_in[5];
    const float* bv  = (const float*)d_in[6];
    const float* Wo  = (const float*)d_in[7];
    const float* g1  = (const float*)d_in[8];
    const float* be1 = (const float*)d_in[9];
    const float* W1  = (const float*)d_in[10];
    const float* b1  = (const float*)d_in[11];
    const float* W2  = (const float*)d_in[12];
    const float* g2  = (const float*)d_in[13];
    const float* be2 = (const float*)d_in[14];

    char* w = (char*)d_ws;
    auto alloc = [&](size_t bytes) {
        char* p = w;
        w += (bytes + 255) & ~(size_t)255;
        return p;
    };
    u16* wqkv_t = (u16*)alloc((size_t)NQKV * D_MODEL * 2);
    u16* wo_t   = (u16*)alloc((size_t)D_MODEL * D_MODEL * 2);
    u16* w1_t   = (u16*)alloc((size_t)DFF * D_MODEL * 2);
    u16* w2_t   = (u16*)alloc((size_t)D_MODEL * DFF * 2);
    float* bqkv = (float*)alloc((size_t)NQKV * 4);
    u16* x_bf   = (u16*)alloc((size_t)BL * D_MODEL * 2);
    u16* qkvbuf = (u16*)alloc((size_t)BL * NQKV * 2);
    u16* vtbuf  = (u16*)alloc((size_t)BATCH * NH * DK * SEQ * 2);
    u16* obuf   = (u16*)alloc((size_t)BL * D_MODEL * 2);
    float* mha_p = (float*)alloc((size_t)2 * BL * D_MODEL * 4);  // split-K partials
    u16* h1_bf  = (u16*)alloc((size_t)BL * D_MODEL * 2);
    float* h1_f = (float*)alloc((size_t)BL * D_MODEL * 4);
    u16* ffa    = (u16*)alloc((size_t)BL * DFF * 2);
    float* ffb_p = (float*)alloc((size_t)2 * BL * D_MODEL * 4);  // split-K partials

    cast_f32_bf16<<<dim3(BL * D_MODEL / 1024), 256, 0, stream>>>(x, x_bf);
    transpose_wqkv<<<dim3(16, 16, 3), 256, 0, stream>>>(Wq, Wk, Wv, wqkv_t);
    transpose2d<<<dim3(16, 16), 256, 0, stream>>>(Wo, wo_t, 1024, 1024);
    transpose2d<<<dim3(64, 16), 256, 0, stream>>>(W1, w1_t, 1024, 4096);
    transpose2d<<<dim3(16, 64), 256, 0, stream>>>(W2, w2_t, 4096, 1024);
    concat_bias<<<dim3(12), 256, 0, stream>>>(bq, bk, bv, bqkv);

    // QKV = x @ Wqkv^T + bias -> bf16 [4096][3072]; Q cols pre-scaled
    gemm_bt<0, 0, 1, 1, 1><<<dim3(32, 24), 256, 0, stream>>>(x_bf, wqkv_t, bqkv,
                                                             qkvbuf, BL, NQKV, D_MODEL);
    transpose_v<<<dim3(32, 16, 2), 256, 0, stream>>>(qkvbuf, vtbuf);
    // flash attention -> O bf16 [4096][1024]
    attn_kernel<<<dim3(16, 16, 2), 256, 0, stream>>>(qkvbuf, vtbuf, obuf);
    // mha partials = O @ Wo (split-K=2) -> f32 x2
    gemm_bt<1, 0, 0, 2, 0><<<dim3(32, 8, 2), 256, 0, stream>>>(obuf, wo_t, nullptr,
                                                               mha_p, BL, D_MODEL, D_MODEL);
    // h1 = LN(x + mha_p0 + mha_p1)
    ln3_kernel<<<dim3(BL), 256, 0, stream>>>(x, mha_p, mha_p + (size_t)BL * D_MODEL,
                                             g1, be1, h1_bf, h1_f);
    // ffa = relu(h1 @ W1 + b1) -> bf16 [4096][4096]
    gemm_bt<0, 1, 1, 1, 0><<<dim3(32, 32), 256, 0, stream>>>(h1_bf, w1_t, b1, ffa,
                                                             BL, DFF, D_MODEL);
    // ffb partials = ffa @ W2 (split-K=2) -> f32 x2
    gemm_bt<1, 0, 0, 2, 0><<<dim3(32, 8, 2), 256, 0, stream>>>(ffa, w2_t, nullptr,
                                                               ffb_p, BL, D_MODEL, DFF);
    // out = LN(h1 + ffb_p0 + ffb_p1)
    ln3_kernel<<<dim3(BL), 256, 0, stream>>>(h1_f, ffb_p, ffb_p + (size_t)BL * D_MODEL,
                                             g2, be2, nullptr, (float*)d_out);
}

// Round 8
// 397.894 us; speedup vs baseline: 1.1227x; 1.0136x over previous
//
#include <hip/hip_runtime.h>

typedef unsigned short u16;
typedef unsigned int u32;
typedef short bf16x8 __attribute__((ext_vector_type(8)));
typedef float f32x4 __attribute__((ext_vector_type(4)));
typedef unsigned int u32x2 __attribute__((ext_vector_type(2)));

#define D_MODEL 1024
#define NH 16
#define DK 64
#define DFF 4096
#define BATCH 2
#define SEQ 2048
#define BL (BATCH*SEQ)
#define NQKV 3072
// fold (1/sqrt(64)) * log2(e) into Q so softmax is raw exp2
#define Q_SCALE 0.18033688011f

__device__ __forceinline__ float bfraw2f(u16 u) {
    union { u32 i; float f; } c; c.i = ((u32)u) << 16; return c.f;
}
__device__ __forceinline__ u16 f2bfraw(float f) {
    union { float f; u32 i; } c; c.f = f;
    u32 i = c.i;
    u32 lsb = (i >> 16) & 1u;
    i += 0x7fffu + lsb;
    return (u16)(i >> 16);
}
__device__ __forceinline__ u32 fasu(float f) {
    union { float f; u32 i; } c; c.f = f; return c.i;
}
// pack two f32 -> (bf16(hi)<<16)|bf16(lo), round-to-nearest via +0x8000
__device__ __forceinline__ u32 pack_bf2(float lo, float hi) {
    return __builtin_amdgcn_perm(fasu(hi) + 0x8000u, fasu(lo) + 0x8000u,
                                 0x07060302u);
}
// async global->LDS 16B per lane (dest = wave-uniform base + lane*16)
__device__ __forceinline__ void gload_lds16(const u16* g, u16* l) {
    __builtin_amdgcn_global_load_lds(
        (const __attribute__((address_space(1))) void*)g,
        (__attribute__((address_space(3))) void*)l, 16, 0, 0);
}

// ---------------- f32 -> bf16 cast ----------------
__global__ __launch_bounds__(256) void cast_f32_bf16(const float* __restrict__ in,
                                                     u16* __restrict__ out) {
    int i = (blockIdx.x * 256 + threadIdx.x) * 4;
    f32x4 v = *(const f32x4*)&in[i];
#pragma unroll
    for (int j = 0; j < 4; j++) out[i + j] = f2bfraw(v[j]);
}

// ---------------- transposes (f32 weights -> bf16 B^T layout) ----------------

__global__ __launch_bounds__(256) void transpose2d(const float* __restrict__ in,
                                                   u16* __restrict__ out,
                                                   int R, int C) {
    __shared__ u16 t[64][65];
    int c0 = blockIdx.x * 64, r0 = blockIdx.y * 64;
    int col = threadIdx.x & 63, rr = threadIdx.x >> 6;
    for (int i = rr; i < 64; i += 4)
        t[i][col] = f2bfraw(in[(size_t)(r0 + i) * C + c0 + col]);
    __syncthreads();
    for (int i = rr; i < 64; i += 4)
        out[(size_t)(c0 + i) * R + r0 + col] = t[col][i];
}

__global__ __launch_bounds__(256) void transpose_wqkv(const float* __restrict__ Wq,
                                                      const float* __restrict__ Wk,
                                                      const float* __restrict__ Wv,
                                                      u16* __restrict__ out) {
    __shared__ u16 t[64][65];
    int d0 = blockIdx.x * 64;
    int h = blockIdx.y;
    int ms = blockIdx.z;
    const float* W = (ms == 0) ? Wq : (ms == 1) ? Wk : Wv;
    const float* src = W + (size_t)h * D_MODEL * DK;
    int col = threadIdx.x & 63, rr = threadIdx.x >> 6;
    for (int i = rr; i < 64; i += 4)
        t[i][col] = f2bfraw(src[(size_t)(d0 + i) * DK + col]);
    __syncthreads();
    u16* dst = out + (size_t)(ms * 1024 + h * 64) * D_MODEL;
    for (int i = rr; i < 64; i += 4)
        dst[(size_t)i * D_MODEL + d0 + col] = t[col][i];
}

__global__ __launch_bounds__(256) void transpose_v(const u16* __restrict__ qkv,
                                                   u16* __restrict__ vt) {
    __shared__ u16 t[64][65];
    int l0 = blockIdx.x * 64;
    int h = blockIdx.y;
    int b = blockIdx.z;
    int col = threadIdx.x & 63, rr = threadIdx.x >> 6;
    const u16* src = qkv + (size_t)(b * SEQ) * NQKV + 2048 + h * 64;
    for (int i = rr; i < 64; i += 4)
        t[i][col] = src[(size_t)(l0 + i) * NQKV + col];
    __syncthreads();
    u16* dst = vt + (size_t)((b * NH + h) * 64) * SEQ;
    for (int i = rr; i < 64; i += 4)
        dst[(size_t)i * SEQ + l0 + col] = t[col][i];
}

__global__ __launch_bounds__(256) void concat_bias(const float* __restrict__ bq,
                                                   const float* __restrict__ bk,
                                                   const float* __restrict__ bv,
                                                   float* __restrict__ out) {
    int i = blockIdx.x * 256 + threadIdx.x;
    out[i] = (i < 1024) ? bq[i] : (i < 2048) ? bk[i - 1024] : bv[i - 2048];
}

// ---------------- GEMM: C[M][N] = A[M][K] @ Bt[N][K]^T ----------------
// m97 structure: 128x128 tile, BK=64, unpadded LDS, global_load_lds width 16.

template <int OUT_F32, int RELU, int HASBIAS, int SPLITK, int SCALEQ>
__global__ __launch_bounds__(256, 4) void gemm_bt(const u16* __restrict__ A,
                                                  const u16* __restrict__ Bt,
                                                  const float* __restrict__ bias,
                                                  void* __restrict__ Cout,
                                                  int M, int N, int K) {
    __shared__ __attribute__((aligned(16))) u16 As[128 * 64];
    __shared__ __attribute__((aligned(16))) u16 Bs[128 * 64];
    const int tid = threadIdx.x;
    const int lane = tid & 63, wid = tid >> 6;
    const int quad = lane >> 4, l16 = lane & 15;
    const int m0 = blockIdx.x * 128, n0 = blockIdx.y * 128;
    const int z = (SPLITK > 1) ? blockIdx.z : 0;
    const int Klen = K / SPLITK;
    const int kend = (z + 1) * Klen;
    const int wm = (wid >> 1) * 64, wn = (wid & 1) * 64;

    f32x4 acc[4][4];
#pragma unroll
    for (int i = 0; i < 4; i++)
#pragma unroll
        for (int j = 0; j < 4; j++) acc[i][j] = (f32x4){0.f, 0.f, 0.f, 0.f};

    const int srow = lane >> 3, scol = (lane & 7) * 8;

    for (int kb = z * Klen; kb < kend; kb += 64) {
#pragma unroll
        for (int p = 0; p < 4; p++) {
            int c = wid * 4 + p;
            int row = c * 8 + srow;
            gload_lds16(&A[(size_t)(m0 + row) * K + kb + scol], &As[c * 512]);
            gload_lds16(&Bt[(size_t)(n0 + row) * K + kb + scol], &Bs[c * 512]);
        }
        __syncthreads();
#pragma unroll
        for (int kh = 0; kh < 2; kh++) {
            bf16x8 af[4], bf[4];
#pragma unroll
            for (int t = 0; t < 4; t++) {
                af[t] = *(const bf16x8*)&As[(wm + t * 16 + l16) * 64 + kh * 32 + quad * 8];
                bf[t] = *(const bf16x8*)&Bs[(wn + t * 16 + l16) * 64 + kh * 32 + quad * 8];
            }
#pragma unroll
            for (int i = 0; i < 4; i++)
#pragma unroll
                for (int j = 0; j < 4; j++)
                    acc[i][j] = __builtin_amdgcn_mfma_f32_16x16x32_bf16(
                        af[i], bf[j], acc[i][j], 0, 0, 0);
        }
        __syncthreads();
    }

    float* outf = (float*)Cout + (size_t)z * M * N;
#pragma unroll
    for (int i = 0; i < 4; i++) {
#pragma unroll
        for (int j = 0; j < 4; j++) {
#pragma unroll
            for (int r = 0; r < 4; r++) {
                int row = m0 + wm + i * 16 + quad * 4 + r;
                int col = n0 + wn + j * 16 + l16;
                float v = acc[i][j][r];
                if (HASBIAS) v += bias[col];
                if (RELU) v = v > 0.f ? v : 0.f;
                if (SCALEQ && col < 1024) v *= Q_SCALE;
                if (OUT_F32)
                    outf[(size_t)row * N + col] = v;
                else
                    ((u16*)Cout)[(size_t)row * N + col] = f2bfraw(v);
            }
        }
    }
}

// ---------------- flash attention, S^T form (r5 structure + exp2 fold) -------
// grid (SEQ/128, NH, BATCH); 4 waves/block; wave owns 32 q rows.
// K-frags shared across qt in regs; V-frags shared across pf0/pf1.
// LDS = 18432 + 17408 + 34816 = 70656 B -> 2 blocks/CU.
__global__ __launch_bounds__(256, 2) void attn_kernel(const u16* __restrict__ qkv,
                                                      const u16* __restrict__ vt,
                                                      u16* __restrict__ O) {
    constexpr int LDK = 72;    // 144B row stride
    constexpr int LDV = 136;   // 272B row stride
    constexpr int LDP = 136;
    __shared__ __attribute__((aligned(16))) u16 Ks[128 * LDK];
    __shared__ __attribute__((aligned(16))) u16 Vs[64 * LDV];
    __shared__ __attribute__((aligned(16))) u16 Ps[4][32 * LDP];

    const int tid = threadIdx.x;
    const int lane = tid & 63, wid = tid >> 6;
    const int quad = lane >> 4, l16 = lane & 15;
    const int b = blockIdx.z, h = blockIdx.y;
    const int q0 = blockIdx.x * 128 + wid * 32;

    // Q fragments (B-operand: n=q=l16, k=quad*8+j); Q pre-scaled by Q_SCALE
    bf16x8 qf[2][2];
#pragma unroll
    for (int qt = 0; qt < 2; qt++) {
        const size_t qrow = (size_t)(b * SEQ + q0 + qt * 16 + l16) * NQKV + h * DK;
        qf[qt][0] = *(const bf16x8*)&qkv[qrow + quad * 8];
        qf[qt][1] = *(const bf16x8*)&qkv[qrow + 32 + quad * 8];
    }
    const u16* Kbase = qkv + (size_t)(b * SEQ) * NQKV + D_MODEL + h * DK;
    const u16* Vbase = vt + (size_t)((b * NH + h) * DK) * SEQ;

    f32x4 oacc[4][2];
#pragma unroll
    for (int d = 0; d < 4; d++) {
        oacc[d][0] = (f32x4){0.f, 0.f, 0.f, 0.f};
        oacc[d][1] = (f32x4){0.f, 0.f, 0.f, 0.f};
    }
    float lr[2] = {0.f, 0.f};
    const f32x4 Z = {0.f, 0.f, 0.f, 0.f};

    for (int kt = 0; kt < SEQ; kt += 128) {
        // ---- stage K[128][64], V^T[64][128]: coalesced b128 reg round-trip ----
        bf16x8 kreg[4], vreg[4];
#pragma unroll
        for (int p = 0; p < 4; p++) {
            int s = p * 256 + tid;
            kreg[p] = *(const bf16x8*)&Kbase[(size_t)(kt + (s >> 3)) * NQKV + (s & 7) * 8];
            vreg[p] = *(const bf16x8*)&Vbase[(size_t)(s >> 4) * SEQ + kt + (s & 15) * 8];
        }
#pragma unroll
        for (int p = 0; p < 4; p++) {
            int s = p * 256 + tid;
            *(bf16x8*)&Ks[(s >> 3) * LDK + (s & 7) * 8] = kreg[p];
            *(bf16x8*)&Vs[(s >> 4) * LDV + (s & 15) * 8] = vreg[p];
        }
        __syncthreads();

        // ---- S^T = K·Q^T : sacc[nt][qt], k=nt*16+quad*4+r, q=qt*16+l16 ----
        f32x4 sacc[8][2];
#pragma unroll
        for (int nt = 0; nt < 8; nt++) {
            const u16* kr = &Ks[(nt * 16 + l16) * LDK];
            bf16x8 kf0 = *(const bf16x8*)&kr[quad * 8];
            bf16x8 kf1 = *(const bf16x8*)&kr[32 + quad * 8];
#pragma unroll
            for (int qt = 0; qt < 2; qt++) {
                f32x4 s0 = __builtin_amdgcn_mfma_f32_16x16x32_bf16(kf0, qf[qt][0], Z, 0, 0, 0);
                sacc[nt][qt] = __builtin_amdgcn_mfma_f32_16x16x32_bf16(kf1, qf[qt][1], s0, 0, 0, 0);
            }
        }

        // ---- softmax: raw exp2 (scale folded into Q), per-lane sums ----
#pragma unroll
        for (int qt = 0; qt < 2; qt++) {
            u16* prow = &Ps[wid][(qt * 16 + l16) * LDP];
#pragma unroll
            for (int nt = 0; nt < 8; nt++) {
                float p0 = exp2f(sacc[nt][qt][0]);
                float p1 = exp2f(sacc[nt][qt][1]);
                float p2 = exp2f(sacc[nt][qt][2]);
                float p3 = exp2f(sacc[nt][qt][3]);
                lr[qt] += (p0 + p1) + (p2 + p3);
                u32x2 w;
                w.x = pack_bf2(p0, p1);
                w.y = pack_bf2(p2, p3);
                *(u32x2*)&prow[nt * 16 + quad * 4] = w;
            }
        }
        // P write->read is same-wave LDS (lgkm-ordered): no barrier needed.

        // ---- O^T += V^T·P^T : A=V frag (LDS, shared), B=P frags ----
#pragma unroll
        for (int ks = 0; ks < 4; ks++) {
            bf16x8 pf0 = *(const bf16x8*)&Ps[wid][l16 * LDP + ks * 32 + quad * 8];
            bf16x8 pf1 = *(const bf16x8*)&Ps[wid][(16 + l16) * LDP + ks * 32 + quad * 8];
#pragma unroll
            for (int d = 0; d < 4; d++) {
                bf16x8 vf = *(const bf16x8*)&Vs[(d * 16 + l16) * LDV + ks * 32 + quad * 8];
                oacc[d][0] = __builtin_amdgcn_mfma_f32_16x16x32_bf16(vf, pf0, oacc[d][0], 0, 0, 0);
                oacc[d][1] = __builtin_amdgcn_mfma_f32_16x16x32_bf16(vf, pf1, oacc[d][1], 0, 0, 0);
            }
        }
        __syncthreads();  // all waves done with Ks/Vs before restage
    }

    // lane's lr covers its quad's 32 k's per tile; reduce across quads
#pragma unroll
    for (int qt = 0; qt < 2; qt++) {
        lr[qt] += __shfl_xor(lr[qt], 16, 64);
        lr[qt] += __shfl_xor(lr[qt], 32, 64);
    }

    // O^T C-layout: col=q=l16(+qt*16), row=dv=d*16+quad*4+r -> b64 stores
#pragma unroll
    for (int qt = 0; qt < 2; qt++) {
        float iv = 1.f / lr[qt];
        size_t row = (size_t)(b * SEQ + q0 + qt * 16 + l16);
#pragma unroll
        for (int d = 0; d < 4; d++) {
            float o0 = oacc[d][qt][0] * iv, o1 = oacc[d][qt][1] * iv;
            float o2 = oacc[d][qt][2] * iv, o3 = oacc[d][qt][3] * iv;
            u32x2 w;
            w.x = ((u32)f2bfraw(o1) << 16) | f2bfraw(o0);
            w.y = ((u32)f2bfraw(o3) << 16) | f2bfraw(o2);
            *(u32x2*)&O[row * D_MODEL + h * DK + d * 16 + quad * 4] = w;
        }
    }
}

// ---------------- LayerNorm(a + b + c), f32 residual stream ----------------
__global__ __launch_bounds__(256) void ln3_kernel(const float* __restrict__ xa,
                                                  const float* __restrict__ xb,
                                                  const float* __restrict__ xc,
                                                  const float* __restrict__ g,
                                                  const float* __restrict__ be,
                                                  u16* __restrict__ out_bf,
                                                  float* __restrict__ out_f) {
    int row = blockIdx.x;
    int tid = threadIdx.x;
    const float* pa = xa + (size_t)row * D_MODEL;
    const float* pb = xb + (size_t)row * D_MODEL;
    const float* pc = xc + (size_t)row * D_MODEL;
    int c = tid * 4;
    f32x4 av = *(const f32x4*)&pa[c];
    f32x4 bv = *(const f32x4*)&pb[c];
    f32x4 cv = *(const f32x4*)&pc[c];
    float v[4];
    float s = 0.f, ss = 0.f;
#pragma unroll
    for (int i = 0; i < 4; i++) {
        v[i] = av[i] + bv[i] + cv[i];
        s += v[i];
        ss += v[i] * v[i];
    }
#pragma unroll
    for (int off = 32; off; off >>= 1) {
        s += __shfl_down(s, off, 64);
        ss += __shfl_down(ss, off, 64);
    }
    __shared__ float red[8];
    int wid = tid >> 6, lane = tid & 63;
    if (lane == 0) { red[wid] = s; red[4 + wid] = ss; }
    __syncthreads();
    if (tid == 0) {
        red[0] = red[0] + red[1] + red[2] + red[3];
        red[4] = red[4] + red[5] + red[6] + red[7];
    }
    __syncthreads();
    float mu = red[0] * (1.f / D_MODEL);
    float var = red[4] * (1.f / D_MODEL) - mu * mu;
    float rs = rsqrtf(var + 1e-5f);
#pragma unroll
    for (int i = 0; i < 4; i++) {
        float o = (v[i] - mu) * rs * g[c + i] + be[c + i];
        if (out_f) out_f[(size_t)row * D_MODEL + c + i] = o;
        if (out_bf) out_bf[(size_t)row * D_MODEL + c + i] = f2bfraw(o);
    }
}

// ---------------- launch ----------------
extern "C" void kernel_launch(void* const* d_in, const int* in_sizes, int n_in,
                              void* d_out, int out_size, void* d_ws, size_t ws_size,
                              hipStream_t stream) {
    const float* x   = (const float*)d_in[0];
    const float* Wq  = (const float*)d_in[1];
    const float* bq  = (const float*)d_in[2];
    const float* Wk  = (const float*)d_in[3];
    const float* bk  = (const float*)d_in[4];
    const float* Wv  = (const float*)d_in[5];
    const float* bv  = (const float*)d_in[6];
    const float* Wo  = (const float*)d_in[7];
    const float* g1  = (const float*)d_in[8];
    const float* be1 = (const float*)d_in[9];
    const float* W1  = (const float*)d_in[10];
    const float* b1  = (const float*)d_in[11];
    const float* W2  = (const float*)d_in[12];
    const float* g2  = (const float*)d_in[13];
    const float* be2 = (const float*)d_in[14];

    char* w = (char*)d_ws;
    auto alloc = [&](size_t bytes) {
        char* p = w;
        w += (bytes + 255) & ~(size_t)255;
        return p;
    };
    u16* wqkv_t = (u16*)alloc((size_t)NQKV * D_MODEL * 2);
    u16* wo_t   = (u16*)alloc((size_t)D_MODEL * D_MODEL * 2);
    u16* w1_t   = (u16*)alloc((size_t)DFF * D_MODEL * 2);
    u16* w2_t   = (u16*)alloc((size_t)D_MODEL * DFF * 2);
    float* bqkv = (float*)alloc((size_t)NQKV * 4);
    u16* x_bf   = (u16*)alloc((size_t)BL * D_MODEL * 2);
    u16* qkvbuf = (u16*)alloc((size_t)BL * NQKV * 2);
    u16* vtbuf  = (u16*)alloc((size_t)BATCH * NH * DK * SEQ * 2);
    u16* obuf   = (u16*)alloc((size_t)BL * D_MODEL * 2);
    float* mha_p = (float*)alloc((size_t)2 * BL * D_MODEL * 4);  // split-K partials
    u16* h1_bf  = (u16*)alloc((size_t)BL * D_MODEL * 2);
    float* h1_f = (float*)alloc((size_t)BL * D_MODEL * 4);
    u16* ffa    = (u16*)alloc((size_t)BL * DFF * 2);
    float* ffb_p = (float*)alloc((size_t)2 * BL * D_MODEL * 4); // split-K partials

    cast_f32_bf16<<<dim3(BL * D_MODEL / 1024), 256, 0, stream>>>(x, x_bf);
    transpose_wqkv<<<dim3(16, 16, 3), 256, 0, stream>>>(Wq, Wk, Wv, wqkv_t);
    transpose2d<<<dim3(16, 16), 256, 0, stream>>>(Wo, wo_t, 1024, 1024);
    transpose2d<<<dim3(64, 16), 256, 0, stream>>>(W1, w1_t, 1024, 4096);
    transpose2d<<<dim3(16, 64), 256, 0, stream>>>(W2, w2_t, 4096, 1024);
    concat_bias<<<dim3(12), 256, 0, stream>>>(bq, bk, bv, bqkv);

    // QKV = x @ Wqkv^T + bias -> bf16 [4096][3072]; Q cols pre-scaled
    gemm_bt<0, 0, 1, 1, 1><<<dim3(32, 24), 256, 0, stream>>>(x_bf, wqkv_t, bqkv,
                                                             qkvbuf, BL, NQKV, D_MODEL);
    transpose_v<<<dim3(32, 16, 2), 256, 0, stream>>>(qkvbuf, vtbuf);
    // flash attention -> O bf16 [4096][1024]
    attn_kernel<<<dim3(16, 16, 2), 256, 0, stream>>>(qkvbuf, vtbuf, obuf);
    // mha partials = O @ Wo (split-K=2) -> f32 x2
    gemm_bt<1, 0, 0, 2, 0><<<dim3(32, 8, 2), 256, 0, stream>>>(obuf, wo_t, nullptr,
                                                               mha_p, BL, D_MODEL, D_MODEL);
    // h1 = LN(x + mha_p0 + mha_p1)
    ln3_kernel<<<dim3(BL), 256, 0, stream>>>(x, mha_p, mha_p + (size_t)BL * D_MODEL,
                                             g1, be1, h1_bf, h1_f);
    // ffa = relu(h1 @ W1 + b1) -> bf16 [4096][4096]
    gemm_bt<0, 1, 1, 1, 0><<<dim3(32, 32), 256, 0, stream>>>(h1_bf, w1_t, b1, ffa,
                                                             BL, DFF, D_MODEL);
    // ffb partials = ffa @ W2 (split-K=2) -> f32 x2
    gemm_bt<1, 0, 0, 2, 0><<<dim3(32, 8, 2), 256, 0, stream>>>(ffa, w2_t, nullptr,
                                                               ffb_p, BL, D_MODEL, DFF);
    // out = LN(h1 + ffb_p0 + ffb_p1)
    ln3_kernel<<<dim3(BL), 256, 0, stream>>>(h1_f, ffb_p, ffb_p + (size_t)BL * D_MODEL,
                                             g2, be2, nullptr, (float*)d_out);
}

// Round 9
// 379.748 us; speedup vs baseline: 1.1763x; 1.0478x over previous
//
#include <hip/hip_runtime.h>

typedef unsigned short u16;
typedef unsigned int u32;
typedef short bf16x8 __attribute__((ext_vector_type(8)));
typedef float f32x4 __attribute__((ext_vector_type(4)));
typedef unsigned int u32x2 __attribute__((ext_vector_type(2)));

#define D_MODEL 1024
#define NH 16
#define DK 64
#define DFF 4096
#define BATCH 2
#define SEQ 2048
#define BL (BATCH*SEQ)
#define NQKV 3072
// fold (1/sqrt(64)) * log2(e) into Q so softmax is raw exp2 (v_exp_f32)
#define Q_SCALE 0.18033688011f

__device__ __forceinline__ float bfraw2f(u16 u) {
    union { u32 i; float f; } c; c.i = ((u32)u) << 16; return c.f;
}
__device__ __forceinline__ u16 f2bfraw(float f) {
    union { float f; u32 i; } c; c.f = f;
    u32 i = c.i;
    u32 lsb = (i >> 16) & 1u;
    i += 0x7fffu + lsb;
    return (u16)(i >> 16);
}
__device__ __forceinline__ u32 fasu(float f) {
    union { float f; u32 i; } c; c.f = f; return c.i;
}
// pack two f32 -> (bf16(hi)<<16)|bf16(lo), round-to-nearest via +0x8000
__device__ __forceinline__ u32 pack_bf2(float lo, float hi) {
    return __builtin_amdgcn_perm(fasu(hi) + 0x8000u, fasu(lo) + 0x8000u,
                                 0x07060302u);
}
// async global->LDS 16B per lane (dest = wave-uniform base + lane*16)
__device__ __forceinline__ void gload_lds16(const u16* g, u16* l) {
    __builtin_amdgcn_global_load_lds(
        (const __attribute__((address_space(1))) void*)g,
        (__attribute__((address_space(3))) void*)l, 16, 0, 0);
}

// ---------------- f32 -> bf16 cast ----------------
__global__ __launch_bounds__(256) void cast_f32_bf16(const float* __restrict__ in,
                                                     u16* __restrict__ out) {
    int i = (blockIdx.x * 256 + threadIdx.x) * 4;
    f32x4 v = *(const f32x4*)&in[i];
#pragma unroll
    for (int j = 0; j < 4; j++) out[i + j] = f2bfraw(v[j]);
}

// ---------------- transposes (f32 weights -> bf16 B^T layout) ----------------

__global__ __launch_bounds__(256) void transpose2d(const float* __restrict__ in,
                                                   u16* __restrict__ out,
                                                   int R, int C) {
    __shared__ u16 t[64][65];
    int c0 = blockIdx.x * 64, r0 = blockIdx.y * 64;
    int col = threadIdx.x & 63, rr = threadIdx.x >> 6;
    for (int i = rr; i < 64; i += 4)
        t[i][col] = f2bfraw(in[(size_t)(r0 + i) * C + c0 + col]);
    __syncthreads();
    for (int i = rr; i < 64; i += 4)
        out[(size_t)(c0 + i) * R + r0 + col] = t[col][i];
}

__global__ __launch_bounds__(256) void transpose_wqkv(const float* __restrict__ Wq,
                                                      const float* __restrict__ Wk,
                                                      const float* __restrict__ Wv,
                                                      u16* __restrict__ out) {
    __shared__ u16 t[64][65];
    int d0 = blockIdx.x * 64;
    int h = blockIdx.y;
    int ms = blockIdx.z;
    const float* W = (ms == 0) ? Wq : (ms == 1) ? Wk : Wv;
    const float* src = W + (size_t)h * D_MODEL * DK;
    int col = threadIdx.x & 63, rr = threadIdx.x >> 6;
    for (int i = rr; i < 64; i += 4)
        t[i][col] = f2bfraw(src[(size_t)(d0 + i) * DK + col]);
    __syncthreads();
    u16* dst = out + (size_t)(ms * 1024 + h * 64) * D_MODEL;
    for (int i = rr; i < 64; i += 4)
        dst[(size_t)i * D_MODEL + d0 + col] = t[col][i];
}

__global__ __launch_bounds__(256) void concat_bias(const float* __restrict__ bq,
                                                   const float* __restrict__ bk,
                                                   const float* __restrict__ bv,
                                                   float* __restrict__ out) {
    int i = blockIdx.x * 256 + threadIdx.x;
    out[i] = (i < 1024) ? bq[i] : (i < 2048) ? bk[i - 1024] : bv[i - 2048];
}

// ---------------- GEMM: C[M][N] = A[M][K] @ Bt[N][K]^T ----------------
// m97 structure: 128x128 tile, BK=64, unpadded LDS, global_load_lds width 16.
// VSTORE: blocks with n0>=2048 (V section of QKV) store transposed into vtout
//         [b][h][dv][l] as 8B packed bf16 (eliminates transpose_v kernel).

template <int OUT_F32, int RELU, int HASBIAS, int SPLITK, int SCALEQ, int VSTORE>
__global__ __launch_bounds__(256, 4) void gemm_bt(const u16* __restrict__ A,
                                                  const u16* __restrict__ Bt,
                                                  const float* __restrict__ bias,
                                                  void* __restrict__ Cout,
                                                  u16* __restrict__ vtout,
                                                  int M, int N, int K) {
    __shared__ __attribute__((aligned(16))) u16 As[128 * 64];
    __shared__ __attribute__((aligned(16))) u16 Bs[128 * 64];
    const int tid = threadIdx.x;
    const int lane = tid & 63, wid = tid >> 6;
    const int quad = lane >> 4, l16 = lane & 15;
    const int m0 = blockIdx.x * 128, n0 = blockIdx.y * 128;
    const int z = (SPLITK > 1) ? blockIdx.z : 0;
    const int Klen = K / SPLITK;
    const int kend = (z + 1) * Klen;
    const int wm = (wid >> 1) * 64, wn = (wid & 1) * 64;

    f32x4 acc[4][4];
#pragma unroll
    for (int i = 0; i < 4; i++)
#pragma unroll
        for (int j = 0; j < 4; j++) acc[i][j] = (f32x4){0.f, 0.f, 0.f, 0.f};

    const int srow = lane >> 3, scol = (lane & 7) * 8;

    for (int kb = z * Klen; kb < kend; kb += 64) {
#pragma unroll
        for (int p = 0; p < 4; p++) {
            int c = wid * 4 + p;
            int row = c * 8 + srow;
            gload_lds16(&A[(size_t)(m0 + row) * K + kb + scol], &As[c * 512]);
            gload_lds16(&Bt[(size_t)(n0 + row) * K + kb + scol], &Bs[c * 512]);
        }
        __syncthreads();
#pragma unroll
        for (int kh = 0; kh < 2; kh++) {
            bf16x8 af[4], bf[4];
#pragma unroll
            for (int t = 0; t < 4; t++) {
                af[t] = *(const bf16x8*)&As[(wm + t * 16 + l16) * 64 + kh * 32 + quad * 8];
                bf[t] = *(const bf16x8*)&Bs[(wn + t * 16 + l16) * 64 + kh * 32 + quad * 8];
            }
#pragma unroll
            for (int i = 0; i < 4; i++)
#pragma unroll
                for (int j = 0; j < 4; j++)
                    acc[i][j] = __builtin_amdgcn_mfma_f32_16x16x32_bf16(
                        af[i], bf[j], acc[i][j], 0, 0, 0);
        }
        __syncthreads();
    }

    if (VSTORE && n0 >= 2048) {
        // V section -> vtout[b][dv][l], dv = col-2048, 4 consecutive l per store
#pragma unroll
        for (int i = 0; i < 4; i++) {
            int row0 = m0 + wm + i * 16 + quad * 4;
            int bb = row0 >> 11, l = row0 & 2047;
#pragma unroll
            for (int j = 0; j < 4; j++) {
                int col = n0 + wn + j * 16 + l16;
                float bv = HASBIAS ? bias[col] : 0.f;
                int dv = col - 2048;
                u32x2 w;
                w.x = pack_bf2(acc[i][j][0] + bv, acc[i][j][1] + bv);
                w.y = pack_bf2(acc[i][j][2] + bv, acc[i][j][3] + bv);
                *(u32x2*)&vtout[((size_t)(bb * 1024 + dv)) * 2048 + l] = w;
            }
        }
        return;
    }

    float* outf = (float*)Cout + (size_t)z * M * N;
#pragma unroll
    for (int i = 0; i < 4; i++) {
#pragma unroll
        for (int j = 0; j < 4; j++) {
#pragma unroll
            for (int r = 0; r < 4; r++) {
                int row = m0 + wm + i * 16 + quad * 4 + r;
                int col = n0 + wn + j * 16 + l16;
                float v = acc[i][j][r];
                if (HASBIAS) v += bias[col];
                if (RELU) v = v > 0.f ? v : 0.f;
                if (SCALEQ && col < 1024) v *= Q_SCALE;
                if (OUT_F32)
                    outf[(size_t)row * N + col] = v;
                else
                    ((u16*)Cout)[(size_t)row * N + col] = f2bfraw(v);
            }
        }
    }
}

// ---------------- flash attention, S^T form (r5 structure, raw v_exp) -------
// grid (SEQ/128, NH, BATCH); 4 waves/block; wave owns 32 q rows.
// K-frags shared across qt in regs; V-frags shared across pf0/pf1.
// LDS = 18432 + 17408 + 34816 = 70656 B -> 2 blocks/CU.
__global__ __launch_bounds__(256, 2) void attn_kernel(const u16* __restrict__ qkv,
                                                      const u16* __restrict__ vt,
                                                      u16* __restrict__ O) {
    constexpr int LDK = 72;    // 144B row stride
    constexpr int LDV = 136;   // 272B row stride
    constexpr int LDP = 136;
    __shared__ __attribute__((aligned(16))) u16 Ks[128 * LDK];
    __shared__ __attribute__((aligned(16))) u16 Vs[64 * LDV];
    __shared__ __attribute__((aligned(16))) u16 Ps[4][32 * LDP];

    const int tid = threadIdx.x;
    const int lane = tid & 63, wid = tid >> 6;
    const int quad = lane >> 4, l16 = lane & 15;
    const int b = blockIdx.z, h = blockIdx.y;
    const int q0 = blockIdx.x * 128 + wid * 32;

    // Q fragments (B-operand: n=q=l16, k=quad*8+j); Q pre-scaled by Q_SCALE
    bf16x8 qf[2][2];
#pragma unroll
    for (int qt = 0; qt < 2; qt++) {
        const size_t qrow = (size_t)(b * SEQ + q0 + qt * 16 + l16) * NQKV + h * DK;
        qf[qt][0] = *(const bf16x8*)&qkv[qrow + quad * 8];
        qf[qt][1] = *(const bf16x8*)&qkv[qrow + 32 + quad * 8];
    }
    const u16* Kbase = qkv + (size_t)(b * SEQ) * NQKV + D_MODEL + h * DK;
    const u16* Vbase = vt + (size_t)((b * NH + h) * DK) * SEQ;

    f32x4 oacc[4][2];
#pragma unroll
    for (int d = 0; d < 4; d++) {
        oacc[d][0] = (f32x4){0.f, 0.f, 0.f, 0.f};
        oacc[d][1] = (f32x4){0.f, 0.f, 0.f, 0.f};
    }
    float lr[2] = {0.f, 0.f};
    const f32x4 Z = {0.f, 0.f, 0.f, 0.f};

    for (int kt = 0; kt < SEQ; kt += 128) {
        // ---- stage K[128][64], V^T[64][128]: coalesced b128 reg round-trip ----
        bf16x8 kreg[4], vreg[4];
#pragma unroll
        for (int p = 0; p < 4; p++) {
            int s = p * 256 + tid;
            kreg[p] = *(const bf16x8*)&Kbase[(size_t)(kt + (s >> 3)) * NQKV + (s & 7) * 8];
            vreg[p] = *(const bf16x8*)&Vbase[(size_t)(s >> 4) * SEQ + kt + (s & 15) * 8];
        }
#pragma unroll
        for (int p = 0; p < 4; p++) {
            int s = p * 256 + tid;
            *(bf16x8*)&Ks[(s >> 3) * LDK + (s & 7) * 8] = kreg[p];
            *(bf16x8*)&Vs[(s >> 4) * LDV + (s & 15) * 8] = vreg[p];
        }
        __syncthreads();

        // ---- S^T = K·Q^T : sacc[nt][qt], k=nt*16+quad*4+r, q=qt*16+l16 ----
        f32x4 sacc[8][2];
#pragma unroll
        for (int nt = 0; nt < 8; nt++) {
            const u16* kr = &Ks[(nt * 16 + l16) * LDK];
            bf16x8 kf0 = *(const bf16x8*)&kr[quad * 8];
            bf16x8 kf1 = *(const bf16x8*)&kr[32 + quad * 8];
#pragma unroll
            for (int qt = 0; qt < 2; qt++) {
                f32x4 s0 = __builtin_amdgcn_mfma_f32_16x16x32_bf16(kf0, qf[qt][0], Z, 0, 0, 0);
                sacc[nt][qt] = __builtin_amdgcn_mfma_f32_16x16x32_bf16(kf1, qf[qt][1], s0, 0, 0, 0);
            }
        }

        // ---- softmax: raw v_exp_f32 (scale folded into Q), per-lane sums ----
#pragma unroll
        for (int qt = 0; qt < 2; qt++) {
            u16* prow = &Ps[wid][(qt * 16 + l16) * LDP];
#pragma unroll
            for (int nt = 0; nt < 8; nt++) {
                float p0 = __builtin_amdgcn_exp2f(sacc[nt][qt][0]);
                float p1 = __builtin_amdgcn_exp2f(sacc[nt][qt][1]);
                float p2 = __builtin_amdgcn_exp2f(sacc[nt][qt][2]);
                float p3 = __builtin_amdgcn_exp2f(sacc[nt][qt][3]);
                lr[qt] += (p0 + p1) + (p2 + p3);
                u32x2 w;
                w.x = pack_bf2(p0, p1);
                w.y = pack_bf2(p2, p3);
                *(u32x2*)&prow[nt * 16 + quad * 4] = w;
            }
        }
        // P write->read is same-wave LDS (lgkm-ordered): no barrier needed.

        // ---- O^T += V^T·P^T : A=V frag (LDS, shared), B=P frags ----
#pragma unroll
        for (int ks = 0; ks < 4; ks++) {
            bf16x8 pf0 = *(const bf16x8*)&Ps[wid][l16 * LDP + ks * 32 + quad * 8];
            bf16x8 pf1 = *(const bf16x8*)&Ps[wid][(16 + l16) * LDP + ks * 32 + quad * 8];
#pragma unroll
            for (int d = 0; d < 4; d++) {
                bf16x8 vf = *(const bf16x8*)&Vs[(d * 16 + l16) * LDV + ks * 32 + quad * 8];
                oacc[d][0] = __builtin_amdgcn_mfma_f32_16x16x32_bf16(vf, pf0, oacc[d][0], 0, 0, 0);
                oacc[d][1] = __builtin_amdgcn_mfma_f32_16x16x32_bf16(vf, pf1, oacc[d][1], 0, 0, 0);
            }
        }
        __syncthreads();  // all waves done with Ks/Vs before restage
    }

    // lane's lr covers its quad's 32 k's per tile; reduce across quads
#pragma unroll
    for (int qt = 0; qt < 2; qt++) {
        lr[qt] += __shfl_xor(lr[qt], 16, 64);
        lr[qt] += __shfl_xor(lr[qt], 32, 64);
    }

    // O^T C-layout: col=q=l16(+qt*16), row=dv=d*16+quad*4+r -> b64 stores
#pragma unroll
    for (int qt = 0; qt < 2; qt++) {
        float iv = 1.f / lr[qt];
        size_t row = (size_t)(b * SEQ + q0 + qt * 16 + l16);
#pragma unroll
        for (int d = 0; d < 4; d++) {
            float o0 = oacc[d][qt][0] * iv, o1 = oacc[d][qt][1] * iv;
            float o2 = oacc[d][qt][2] * iv, o3 = oacc[d][qt][3] * iv;
            u32x2 w;
            w.x = ((u32)f2bfraw(o1) << 16) | f2bfraw(o0);
            w.y = ((u32)f2bfraw(o3) << 16) | f2bfraw(o2);
            *(u32x2*)&O[row * D_MODEL + h * DK + d * 16 + quad * 4] = w;
        }
    }
}

// ---------------- LayerNorm(a + b + c), f32 residual stream ----------------
__global__ __launch_bounds__(256) void ln3_kernel(const float* __restrict__ xa,
                                                  const float* __restrict__ xb,
                                                  const float* __restrict__ xc,
                                                  const float* __restrict__ g,
                                                  const float* __restrict__ be,
                                                  u16* __restrict__ out_bf,
                                                  float* __restrict__ out_f) {
    int row = blockIdx.x;
    int tid = threadIdx.x;
    const float* pa = xa + (size_t)row * D_MODEL;
    const float* pb = xb + (size_t)row * D_MODEL;
    const float* pc = xc + (size_t)row * D_MODEL;
    int c = tid * 4;
    f32x4 av = *(const f32x4*)&pa[c];
    f32x4 bv = *(const f32x4*)&pb[c];
    f32x4 cv = *(const f32x4*)&pc[c];
    float v[4];
    float s = 0.f, ss = 0.f;
#pragma unroll
    for (int i = 0; i < 4; i++) {
        v[i] = av[i] + bv[i] + cv[i];
        s += v[i];
        ss += v[i] * v[i];
    }
#pragma unroll
    for (int off = 32; off; off >>= 1) {
        s += __shfl_down(s, off, 64);
        ss += __shfl_down(ss, off, 64);
    }
    __shared__ float red[8];
    int wid = tid >> 6, lane = tid & 63;
    if (lane == 0) { red[wid] = s; red[4 + wid] = ss; }
    __syncthreads();
    if (tid == 0) {
        red[0] = red[0] + red[1] + red[2] + red[3];
        red[4] = red[4] + red[5] + red[6] + red[7];
    }
    __syncthreads();
    float mu = red[0] * (1.f / D_MODEL);
    float var = red[4] * (1.f / D_MODEL) - mu * mu;
    float rs = rsqrtf(var + 1e-5f);
#pragma unroll
    for (int i = 0; i < 4; i++) {
        float o = (v[i] - mu) * rs * g[c + i] + be[c + i];
        if (out_f) out_f[(size_t)row * D_MODEL + c + i] = o;
        if (out_bf) out_bf[(size_t)row * D_MODEL + c + i] = f2bfraw(o);
    }
}

// ---------------- launch ----------------
extern "C" void kernel_launch(void* const* d_in, const int* in_sizes, int n_in,
                              void* d_out, int out_size, void* d_ws, size_t ws_size,
                              hipStream_t stream) {
    const float* x   = (const float*)d_in[0];
    const float* Wq  = (const float*)d_in[1];
    const float* bq  = (const float*)d_in[2];
    const float* Wk  = (const float*)d_in[3];
    const float* bk  = (const float*)d_in[4];
    const float* Wv  = (const float*)d_in[5];
    const float* bv  = (const float*)d_in[6];
    const float* Wo  = (const float*)d_in[7];
    const float* g1  = (const float*)d_in[8];
    const float* be1 = (const float*)d_in[9];
    const float* W1  = (const float*)d_in[10];
    const float* b1  = (const float*)d_in[11];
    const float* W2  = (const float*)d_in[12];
    const float* g2  = (const float*)d_in[13];
    const float* be2 = (const float*)d_in[14];

    char* w = (char*)d_ws;
    auto alloc = [&](size_t bytes) {
        char* p = w;
        w += (bytes + 255) & ~(size_t)255;
        return p;
    };
    u16* wqkv_t = (u16*)alloc((size_t)NQKV * D_MODEL * 2);
    u16* wo_t   = (u16*)alloc((size_t)D_MODEL * D_MODEL * 2);
    u16* w1_t   = (u16*)alloc((size_t)DFF * D_MODEL * 2);
    u16* w2_t   = (u16*)alloc((size_t)D_MODEL * DFF * 2);
    float* bqkv = (float*)alloc((size_t)NQKV * 4);
    u16* x_bf   = (u16*)alloc((size_t)BL * D_MODEL * 2);
    u16* qkvbuf = (u16*)alloc((size_t)BL * NQKV * 2);
    u16* vtbuf  = (u16*)alloc((size_t)BATCH * NH * DK * SEQ * 2);
    u16* obuf   = (u16*)alloc((size_t)BL * D_MODEL * 2);
    float* mha_p = (float*)alloc((size_t)2 * BL * D_MODEL * 4);  // split-K partials
    u16* h1_bf  = (u16*)alloc((size_t)BL * D_MODEL * 2);
    float* h1_f = (float*)alloc((size_t)BL * D_MODEL * 4);
    u16* ffa    = (u16*)alloc((size_t)BL * DFF * 2);
    float* ffb_p = (float*)alloc((size_t)2 * BL * D_MODEL * 4); // split-K partials

    cast_f32_bf16<<<dim3(BL * D_MODEL / 1024), 256, 0, stream>>>(x, x_bf);
    transpose_wqkv<<<dim3(16, 16, 3), 256, 0, stream>>>(Wq, Wk, Wv, wqkv_t);
    transpose2d<<<dim3(16, 16), 256, 0, stream>>>(Wo, wo_t, 1024, 1024);
    transpose2d<<<dim3(64, 16), 256, 0, stream>>>(W1, w1_t, 1024, 4096);
    transpose2d<<<dim3(16, 64), 256, 0, stream>>>(W2, w2_t, 4096, 1024);
    concat_bias<<<dim3(12), 256, 0, stream>>>(bq, bk, bv, bqkv);

    // QKV = x @ Wqkv^T + bias -> Q,K bf16 into qkvbuf; V transposed into vtbuf
    gemm_bt<0, 0, 1, 1, 1, 1><<<dim3(32, 24), 256, 0, stream>>>(
        x_bf, wqkv_t, bqkv, qkvbuf, vtbuf, BL, NQKV, D_MODEL);
    // flash attention -> O bf16 [4096][1024]
    attn_kernel<<<dim3(16, 16, 2), 256, 0, stream>>>(qkvbuf, vtbuf, obuf);
    // mha partials = O @ Wo (split-K=2) -> f32 x2
    gemm_bt<1, 0, 0, 2, 0, 0><<<dim3(32, 8, 2), 256, 0, stream>>>(
        obuf, wo_t, nullptr, mha_p, nullptr, BL, D_MODEL, D_MODEL);
    // h1 = LN(x + mha_p0 + mha_p1)
    ln3_kernel<<<dim3(BL), 256, 0, stream>>>(x, mha_p, mha_p + (size_t)BL * D_MODEL,
                                             g1, be1, h1_bf, h1_f);
    // ffa = relu(h1 @ W1 + b1) -> bf16 [4096][4096]
    gemm_bt<0, 1, 1, 1, 0, 0><<<dim3(32, 32), 256, 0, stream>>>(
        h1_bf, w1_t, b1, ffa, nullptr, BL, DFF, D_MODEL);
    // ffb partials = ffa @ W2 (split-K=2) -> f32 x2
    gemm_bt<1, 0, 0, 2, 0, 0><<<dim3(32, 8, 2), 256, 0, stream>>>(
        ffa, w2_t, nullptr, ffb_p, nullptr, BL, D_MODEL, DFF);
    // out = LN(h1 + ffb_p0 + ffb_p1)
    ln3_kernel<<<dim3(BL), 256, 0, stream>>>(h1_f, ffb_p, ffb_p + (size_t)BL * D_MODEL,
                                             g2, be2, nullptr, (float*)d_out);
}